// Round 7
// baseline (170.373 us; speedup 1.0000x reference)
//
#include <hip/hip_runtime.h>
#include <hip/hip_bf16.h>

// Causal attention B=2,H=12,S=2048,D=64 fp32 in/out.
// R18 = R17 with the P LDS round-trip ELIMINATED via 32x32x16 MFMA + lane^32
// exchange (HK T12 structure, derived for our split-K layout):
//  - QK^T and PV both use mfma_f32_32x32x16_bf16. S^T C-layout (col=q=l&31,
//    row=kv=(reg&3)+8*(reg>>2)+4h) and PV A-layout (row=q=l&31, k=kv=8h+j)
//    share the q<->lane mapping; kv parity mismatch (lane holds residues
//    4h..4h+3 mod 8, needs 0..7) is exactly a lane^32 exchange:
//    per PV step s: own quad qi=2s+h, send quad qi=2s+(1-h) via shfl_xor 32.
//    (verified: lane5/37 @ s=1: own q2/q3, recv kv20-23/24-27 -> j4-7/0-3)
//  - Ps (16KB) deleted -> LDS 48->32KB -> 4 blocks/CU (launch_bounds(256,4)).
//    Per-iter serial chain loses the ds_write P -> ds_read P hop (~2x120cyc).
//  - accl = P*ones via 4x 32x32 MFMA; accl C rows == O C rows -> lane-local
//    normalization (no exchange needed for l).
//  - V LDS layout: V^T [d][kv64] 128B rows, 16B-slot XOR swizzle
//    byte = d*128 + ((kv>>3 ^ (d&7))<<4) + (kv&7)*2. Staging: thread owns
//    4kv x 4d block (kb=(tid&7)*4+((tid&128)>>2), dbase=((tid>>3)&15)*4),
//    4x coalesced f32x4 row loads, in-reg transpose, 4x b64 writes.
//    Round-trip verified (kv=37,d=21 -> byte 2714 both sides); all new LDS
//    accesses 2-way minimum (bank-checked per 16-lane phase group).
//  - K staging/read layout unchanged (R11 pattern, re-derived for 32-row
//    A-frags: byte=(32u+l31)*128 + ((2ks+h ^ (l&7))<<4), 2-way min).
// Carried: fused prep (2 dispatches), split-K chunks of 8 k-tiles (960
// blocks), Q-direct load, single-chunk q-tiles normalize in-register, XCD
// swizzle (3 heads/XCD), dbuf K/V + 1 barrier/iter, bf16 partial O + f32 l,
// BM=128, static-max base-2 softmax, s_setprio around MFMA clusters.
// R13: keep LDS staging. R12: no device-scope sync in-kernel.

#define SEQ 2048
#define DH 64
#define NHEADS 24
#define BN 64
#define LDK 72
#define NSLOT (NHEADS * 16 * 4)                       // 1536
#define WS_FA14  ((size_t)NSLOT * 8192 * 2 + (size_t)NSLOT * 128 * 4)

typedef float f32x4 __attribute__((ext_vector_type(4)));
typedef float f32x16 __attribute__((ext_vector_type(16)));
typedef __bf16 bf16x8 __attribute__((ext_vector_type(8)));
typedef __bf16 bf16x4 __attribute__((ext_vector_type(4)));
typedef unsigned int u32;
typedef u32 u32x2 __attribute__((ext_vector_type(2)));
typedef u32 u32x4 __attribute__((ext_vector_type(4)));

#if __has_builtin(__builtin_amdgcn_exp2f)
#define EXP2F(x) __builtin_amdgcn_exp2f(x)
#else
#define EXP2F(x) exp2f(x)
#endif

#define QSCALE 0.1803368801111204f   // log2(e)/8: folds 1/sqrt(64) + base-2

// ---------------- main: BM=128, split-K(8), dbuf, 32x32 MFMA, reg-P ----------------
__global__ __launch_bounds__(256, 4)
void fa18_kernel(const float* __restrict__ q, const float* __restrict__ k,
                 const float* __restrict__ v,
                 __bf16* __restrict__ opart, float* __restrict__ lpart,
                 float* __restrict__ out)
{
    const int bx = blockIdx.x;             // 960 = 8 XCDs x 3 headgrp x 40
    const int xcd = bx & 7;
    const int sub = bx >> 3;               // 0..119
    const int bh = (sub / 40) * 8 + xcd;   // 3 heads pinned per XCD
    const int rem = 39 - (sub % 40);       // heavy-first within XCD
    int mt2, st;
    if      (rem >= 36) { mt2 = 15; st = 36; }
    else if (rem >= 32) { mt2 = 14; st = 32; }
    else if (rem >= 28) { mt2 = 13; st = 28; }
    else if (rem >= 24) { mt2 = 12; st = 24; }
    else if (rem >= 21) { mt2 = 11; st = 21; }
    else if (rem >= 18) { mt2 = 10; st = 18; }
    else if (rem >= 15) { mt2 = 9;  st = 15; }
    else if (rem >= 12) { mt2 = 8;  st = 12; }
    else if (rem >= 10) { mt2 = 7;  st = 10; }
    else if (rem >= 8)  { mt2 = 6;  st = 8; }
    else if (rem >= 6)  { mt2 = 5;  st = 6; }
    else if (rem >= 4)  { mt2 = 4;  st = 4; }
    else                { mt2 = rem; st = rem; }
    const int chunk = rem - st;
    const int jt0 = chunk * 8;
    const int jt_end = min(jt0 + 8, 2 * mt2 + 2);
    const int q0 = mt2 * 128;

    const int tid = threadIdx.x;
    const int w = tid >> 6, lane = tid & 63;
    const int l31 = lane & 31;
    const int hb = lane >> 5;              // 0/1 half of wave
    const bool ish = (hb != 0);

    __shared__ __bf16 Ks[2][4096];         // 16 KB double-buffered [kv][d] swz
    __shared__ __bf16 Vs[2][4096];         // 16 KB, V^T [d][kv] swz

    const float* kh = k + (size_t)bh * SEQ * DH;
    const float* vh = v + (size_t)bh * SEQ * DH;
    const int qg = q0 + w * 32 + l31;      // this lane's q-row (global)

    // Q fragments, B-operand layout for 32x32x16: col=l31, k=16ks+8hb+j
    bf16x8 qn[4];
    {
        const float* qp = q + (size_t)bh * SEQ * DH + (size_t)qg * DH + hb * 8;
        #pragma unroll
        for (int ks = 0; ks < 4; ++ks) {
            f32x4 x0 = *(const f32x4*)(qp + 16 * ks);
            f32x4 x1 = *(const f32x4*)(qp + 16 * ks + 4);
            #pragma unroll
            for (int j = 0; j < 4; ++j) {
                qn[ks][j]     = (__bf16)(x0[j] * QSCALE);
                qn[ks][4 + j] = (__bf16)(x1[j] * QSCALE);
            }
        }
    }

    bf16x8 ones;
    #pragma unroll
    for (int j = 0; j < 8; ++j) ones[j] = (__bf16)1.0f;

    f32x16 acc_o0 = {}, acc_o1 = {};       // O [q x d]: dt=0,1
    f32x16 accl = {};                      // l (all cols equal)

    // K staging map (R11-identical): rows srow0, srow0+32
    const int srow0 = tid >> 3;
    const int sg    = tid & 7;
    const int klg   = sg ^ (srow0 & 7);

    // V staging map: thread owns 4kv x 4d; bank bits in tid[3:0]
    const int kb    = (tid & 7) * 4 + ((tid & 128) >> 2);
    const int dbase = ((tid >> 3) & 15) * 4;

    f32x4 ka[2][2], va[4];
    auto issueKV = [&](int jt) {
        const float* kp = kh + (size_t)(jt * BN + srow0) * DH + klg * 8;
        ka[0][0] = *(const f32x4*)kp;
        ka[0][1] = *(const f32x4*)(kp + 4);
        kp += 32 * DH;
        ka[1][0] = *(const f32x4*)kp;
        ka[1][1] = *(const f32x4*)(kp + 4);
        const float* vpx = vh + (size_t)(jt * BN + kb) * DH + dbase;
        #pragma unroll
        for (int ii = 0; ii < 4; ++ii) va[ii] = *(const f32x4*)(vpx + ii * DH);
    };
    auto commitKV = [&](int b) {
        #pragma unroll
        for (int s = 0; s < 2; ++s) {
            bf16x8 o;
            #pragma unroll
            for (int jj = 0; jj < 4; ++jj) {
                o[jj]     = (__bf16)ka[s][0][jj];
                o[4 + jj] = (__bf16)ka[s][1][jj];
            }
            *(bf16x8*)((char*)Ks[b] + s * 4096 + tid * 16) = o;
        }
        #pragma unroll
        for (int dd = 0; dd < 4; ++dd) {   // in-register 4x4 transpose, b64 out
            const int d = dbase + dd;
            bf16x4 p4v;
            #pragma unroll
            for (int ii = 0; ii < 4; ++ii) p4v[ii] = (__bf16)va[ii][dd];
            *(bf16x4*)((char*)Vs[b] + d * 128 +
                       ((((kb >> 3) ^ (d & 7)) << 4) | ((kb & 7) * 2))) = p4v;
        }
    };

    // ---- prologue: tile jt0 -> buf0; issue loads for jt0+1 ----
    issueKV(jt0);
    commitKV(0);
    if (jt0 + 1 < jt_end) issueKV(jt0 + 1);
    __syncthreads();

    int buf = 0;
    for (int jt = jt0; jt < jt_end; ++jt) {
        if (jt + 1 < jt_end) commitKV(buf ^ 1);
        if (jt + 2 < jt_end) issueKV(jt + 2);

        // ---- S^T = K * Q^T (2 kv-tiles x 4 k-steps, 8 MFMA) ----
        const char* Kb = (const char*)Ks[buf];
        const char* Vb = (const char*)Vs[buf];
        f32x16 sa0 = {}, sa1 = {};
        __builtin_amdgcn_s_setprio(1);
        #pragma unroll
        for (int ks = 0; ks < 4; ++ks) {
            bf16x8 kf0 = *(const bf16x8*)(Kb + l31 * 128 +
                                          (((2 * ks + hb) ^ (lane & 7)) << 4));
            bf16x8 kf1 = *(const bf16x8*)(Kb + (32 + l31) * 128 +
                                          (((2 * ks + hb) ^ (lane & 7)) << 4));
            sa0 = __builtin_amdgcn_mfma_f32_32x32x16_bf16(kf0, qn[ks], sa0, 0, 0, 0);
            sa1 = __builtin_amdgcn_mfma_f32_32x32x16_bf16(kf1, qn[ks], sa1, 0, 0, 0);
        }
        __builtin_amdgcn_s_setprio(0);

        if (jt >= 2 * mt2) {               // diagonal region: causal mask
            #pragma unroll
            for (int reg = 0; reg < 16; ++reg) {
                const int kvr = jt * 64 + (reg & 3) + 8 * (reg >> 2) + 4 * hb;
                if (kvr > qg)      sa0[reg] = -1e30f;
                if (kvr + 32 > qg) sa1[reg] = -1e30f;
            }
        }

        // ---- p = 2^s -> bf16 quads packed as u32 pairs (all static idx) ----
        u32 pk[8][2];
        #pragma unroll
        for (int sp = 0; sp < 4; ++sp) {
            bf16x4 qd0, qd1;
            #pragma unroll
            for (int r = 0; r < 4; ++r) {
                qd0[r] = (__bf16)EXP2F(sa0[sp * 4 + r]);
                qd1[r] = (__bf16)EXP2F(sa1[sp * 4 + r]);
            }
            u32x2 t0 = *(u32x2*)&qd0;
            u32x2 t1 = *(u32x2*)&qd1;
            pk[sp][0] = t0[0];     pk[sp][1] = t0[1];
            pk[4 + sp][0] = t1[0]; pk[4 + sp][1] = t1[1];
        }

        // ---- O += P V ; l += P*ones. P A-frags via lane^32 exchange ----
        __builtin_amdgcn_s_setprio(1);
        #pragma unroll
        for (int s = 0; s < 4; ++s) {
            // own quad qi=2s+hb, send quad qi=2s+(1-hb)
            u32 sd0 = ish ? pk[2 * s][0] : pk[2 * s + 1][0];
            u32 sd1 = ish ? pk[2 * s][1] : pk[2 * s + 1][1];
            u32 r0 = (u32)__shfl_xor((int)sd0, 32, 64);
            u32 r1 = (u32)__shfl_xor((int)sd1, 32, 64);
            u32x4 wv;
            wv[0] = ish ? r0 : pk[2 * s][0];
            wv[1] = ish ? r1 : pk[2 * s][1];
            wv[2] = ish ? pk[2 * s + 1][0] : r0;
            wv[3] = ish ? pk[2 * s + 1][1] : r1;
            bf16x8 pf = *(bf16x8*)&wv;
            accl = __builtin_amdgcn_mfma_f32_32x32x16_bf16(pf, ones, accl, 0, 0, 0);
            bf16x8 vf0 = *(const bf16x8*)(Vb + l31 * 128 +
                                          (((2 * s + hb) ^ (lane & 7)) << 4));
            bf16x8 vf1 = *(const bf16x8*)(Vb + (32 + l31) * 128 +
                                          (((2 * s + hb) ^ (lane & 7)) << 4));
            acc_o0 = __builtin_amdgcn_mfma_f32_32x32x16_bf16(pf, vf0, acc_o0, 0, 0, 0);
            acc_o1 = __builtin_amdgcn_mfma_f32_32x32x16_bf16(pf, vf1, acc_o1, 0, 0, 0);
        }
        __builtin_amdgcn_s_setprio(0);

        if (jt + 1 < jt_end) __syncthreads();
        buf ^= 1;
    }

    if (2 * mt2 + 2 <= 8) {
        // ---- single-chunk q-tile: normalize in-register (accl rows==O rows)
        float* oh = out + (size_t)bh * SEQ * DH;
        #pragma unroll
        for (int reg = 0; reg < 16; ++reg) {
            const int row = q0 + w * 32 + (reg & 3) + 8 * (reg >> 2) + 4 * hb;
            const float inv = 1.0f / accl[reg];
            oh[(size_t)row * DH + l31]      = acc_o0[reg] * inv;
            oh[(size_t)row * DH + 32 + l31] = acc_o1[reg] * inv;
        }
    } else {
        // ---- partials out (O in bf16; l in f32) ----
        const int slot = (bh * 16 + mt2) * 4 + chunk;
        __bf16* po = opart + (size_t)slot * 8192;
        #pragma unroll
        for (int reg = 0; reg < 16; ++reg) {
            const int row = w * 32 + (reg & 3) + 8 * (reg >> 2) + 4 * hb;
            po[row * 64 + l31]      = (__bf16)acc_o0[reg];
            po[row * 64 + 32 + l31] = (__bf16)acc_o1[reg];
            if (l31 == 0) lpart[(size_t)slot * 128 + row] = accl[reg];
        }
    }
}

// ---------------- reduce: sum bf16 chunks, normalize (mt2 >= 4 only) ----------------
__global__ __launch_bounds__(256)
void fa_reduce(const __bf16* __restrict__ opart, const float* __restrict__ lpart,
               float* __restrict__ out)
{
    const int bx = blockIdx.x;             // 288 = 8 XCDs x 3 headgrp x 12
    const int xcd = bx & 7;
    const int r2 = bx >> 3;                // 0..35
    const int bh = (r2 / 12) * 8 + xcd;    // co-locate with producer XCD
    const int mt2 = 4 + (r2 % 12);
    const int nc = (mt2 >> 2) + 1;         // ceil((2*mt2+2)/8)
    const int base = (bh * 16 + mt2) * 4;
    const int tid = threadIdx.x;
    #pragma unroll
    for (int rnd = 0; rnd < 8; ++rnd) {
        const int flat = rnd * 1024 + tid * 4;
        const int row = flat >> 6;
        float o0 = 0, o1 = 0, o2 = 0, o3 = 0, l = 0;
        for (int c = 0; c < nc; ++c) {
            bf16x4 ov = *(const bf16x4*)(opart + (size_t)(base + c) * 8192 + flat);
            o0 += (float)ov[0]; o1 += (float)ov[1]; o2 += (float)ov[2]; o3 += (float)ov[3];
            l += lpart[(size_t)(base + c) * 128 + row];
        }
        const float inv = 1.0f / l;
        f32x4 res = { o0 * inv, o1 * inv, o2 * inv, o3 * inv };
        *(f32x4*)(out + (size_t)bh * SEQ * DH + (size_t)mt2 * 8192 + flat) = res;
    }
}

// ---------------- fallback: R1 self-contained kernel ----------------
__global__ __launch_bounds__(256, 2)
void fa_causal_kernel(const float* __restrict__ q, const float* __restrict__ k,
                      const float* __restrict__ v, float* __restrict__ out)
{
    const int mt = 31 - (blockIdx.x & 31);
    const int bh = blockIdx.x >> 5;
    const int tid = threadIdx.x;
    const int w = tid >> 6, lane = tid & 63;
    const int g = lane >> 4, li = lane & 15;
    const int m0 = mt * 64;
    __shared__ __bf16 KsF[BN][LDK];
    __shared__ __bf16 VsF[DH][LDK];
    __shared__ __bf16 PsF[4][16][LDK];
    const size_t head_off = (size_t)bh * SEQ * DH;
    const float* qh = q + head_off;
    const float* kh = k + head_off;
    const float* vh = v + head_off;
    float* oh = out + head_off;
    const int qrow = m0 + w * 16 + li;
    bf16x8 qf[2];
    {
        const float* qp = qh + (size_t)qrow * DH + g * 8;
        #pragma unroll
        for (int c = 0; c < 2; ++c) {
            const float* p = qp + c * 32;
            #pragma unroll
            for (int jj = 0; jj < 8; ++jj) qf[c][jj] = (__bf16)p[jj];
        }
    }
    f32x4 acc[4] = {};
    float mrow[4], lrow[4];
    #pragma unroll
    for (int r = 0; r < 4; ++r) { mrow[r] = -1e30f; lrow[r] = 0.0f; }
    const float scale = 0.125f;
    const int srow = tid >> 2, scol = (tid & 3) * 16;
    for (int jt = 0; jt <= mt; ++jt) {
        const int kv0 = jt * BN;
        __syncthreads();
        {
            const float* kp = kh + (size_t)(kv0 + srow) * DH + scol;
            __bf16 tmp[16];
            #pragma unroll
            for (int jj = 0; jj < 16; ++jj) tmp[jj] = (__bf16)kp[jj];
            *(bf16x8*)&KsF[srow][scol]     = *(bf16x8*)&tmp[0];
            *(bf16x8*)&KsF[srow][scol + 8] = *(bf16x8*)&tmp[8];
            const float* vp = vh + (size_t)(kv0 + srow) * DH + scol;
            #pragma unroll
            for (int jj = 0; jj < 16; ++jj) VsF[scol + jj][srow] = (__bf16)vp[jj];
        }
        __syncthreads();
        float s4[4][4];
        #pragma unroll
        for (int t = 0; t < 4; ++t) {
            f32x4 sa = {};
            #pragma unroll
            for (int c = 0; c < 2; ++c) {
                bf16x8 kfr = *(const bf16x8*)&KsF[t * 16 + li][c * 32 + g * 8];
                sa = __builtin_amdgcn_mfma_f32_16x16x32_bf16(qf[c], kfr, sa, 0, 0, 0);
            }
            #pragma unroll
            for (int r = 0; r < 4; ++r) s4[t][r] = sa[r] * scale;
        }
        if (jt == mt) {
            #pragma unroll
            for (int t = 0; t < 4; ++t) {
                const int col = kv0 + t * 16 + li;
                #pragma unroll
                for (int r = 0; r < 4; ++r)
                    if (col > m0 + w * 16 + g * 4 + r) s4[t][r] = -1e30f;
            }
        }
        #pragma unroll
        for (int r = 0; r < 4; ++r) {
            float mx = fmaxf(fmaxf(s4[0][r], s4[1][r]), fmaxf(s4[2][r], s4[3][r]));
            #pragma unroll
            for (int off = 1; off < 16; off <<= 1)
                mx = fmaxf(mx, __shfl_xor(mx, off, 64));
            const float mnew = fmaxf(mrow[r], mx);
            const float alpha = __expf(mrow[r] - mnew);
            mrow[r] = mnew;
            float ps = 0.0f;
            #pragma unroll
            for (int t = 0; t < 4; ++t) {
                const float p = __expf(s4[t][r] - mnew);
                s4[t][r] = p;
                ps += p;
            }
            #pragma unroll
            for (int off = 1; off < 16; off <<= 1)
                ps += __shfl_xor(ps, off, 64);
            lrow[r] = lrow[r] * alpha + ps;
            #pragma unroll
            for (int t = 0; t < 4; ++t) acc[t][r] *= alpha;
        }
        #pragma unroll
        for (int t = 0; t < 4; ++t)
            #pragma unroll
            for (int r = 0; r < 4; ++r)
                PsF[w][g * 4 + r][t * 16 + li] = (__bf16)s4[t][r];
        __syncthreads();
        #pragma unroll
        for (int c = 0; c < 2; ++c) {
            bf16x8 pf = *(const bf16x8*)&PsF[w][li][c * 32 + g * 8];
            #pragma unroll
            for (int t = 0; t < 4; ++t) {
                bf16x8 vfr = *(const bf16x8*)&VsF[t * 16 + li][c * 32 + g * 8];
                acc[t] = __builtin_amdgcn_mfma_f32_16x16x32_bf16(pf, vfr, acc[t], 0, 0, 0);
            }
        }
    }
    #pragma unroll
    for (int r = 0; r < 4; ++r) {
        const int row = m0 + w * 16 + g * 4 + r;
        const float inv = 1.0f / lrow[r];
        float* op = oh + (size_t)row * DH + li;
        #pragma unroll
        for (int t = 0; t < 4; ++t) op[t * 16] = acc[t][r] * inv;
    }
}

extern "C" void kernel_launch(void* const* d_in, const int* in_sizes, int n_in,
                              void* d_out, int out_size, void* d_ws, size_t ws_size,
                              hipStream_t stream) {
    (void)in_sizes; (void)n_in; (void)out_size;
    const float* q = (const float*)d_in[0];
    const float* k = (const float*)d_in[1];
    const float* v = (const float*)d_in[2];
    float* out = (float*)d_out;

    if (ws_size >= WS_FA14) {
        __bf16* opart = (__bf16*)d_ws;
        float* lpart = (float*)((char*)d_ws + (size_t)NSLOT * 8192 * 2);
        fa18_kernel<<<dim3(960), dim3(256), 0, stream>>>(q, k, v, opart, lpart, out);
        fa_reduce<<<dim3(288), dim3(256), 0, stream>>>(opart, lpart, out);
    } else {
        fa_causal_kernel<<<dim3(NHEADS * 32), dim3(256), 0, stream>>>(q, k, v, out);
    }
}

// Round 8
// 169.332 us; speedup vs baseline: 1.0061x; 1.0061x over previous
//
#include <hip/hip_runtime.h>
#include <hip/hip_bf16.h>

// Causal attention B=2,H=12,S=2048,D=64 fp32 in/out.
// R19 = R18 (32x32 MFMA + lane^32 reg-P; CORRECT but 80us) with the two
// PROFILED spill causes fixed. R18 counters: WRITE_SIZE 17->127MB = scratch.
//  (a) address-of-local vector reinterprets (*(u32x2*)&qd0, *(bf16x8*)&wv)
//      forced locals into scratch -> per-iter spill round-trips. Fix: ALL
//      packing via __builtin_bit_cast / element ops (register-only).
//  (b) VGPR over-budget under launch_bounds(256,4) cap=128: 3x f32x16 accs.
//      Fix: accl MFMA DELETED -- in the S^T layout each lane holds P for its
//      own q-row (q=l31), so l = lane-local f32 sum of its 32 exp2 values
//      (+ one shfl_xor(32) at epilogue). Kills 4/20 MFMAs/iter, the ones
//      reg, 15 VGPRs. Eager in-place exp2->pack: sa (32 f32) dies at end of
//      softmax, pk (16 u32) carries P. Peak ~121 VGPR < 128.
// Epilogue: partials path lane-writes lpart[w*32+l31] (lane owns its row's
// l); single-chunk path broadcasts l per reg-row via 16 one-time shfls.
// Carried from R18: mfma_f32_32x32x16 for QK+PV; S^T C-layout col=q=l&31,
// row=kv=(reg&3)+8*(reg>>2)+4h; PV A-frag kv-parity fixed by lane^32
// exchange (own quad 2s+h, send 2s+(1-h)); V^T [d][kv] 16B-XOR LDS (byte=
// d*128+((kv>>3 ^ d&7)<<4)+(kv&7)*2); K layout R11; Ps deleted, LDS 32KB.
// Carried: fused prep (2 dispatches), split-K chunks of 8 k-tiles (960
// blocks), Q-direct, single-chunk q-tiles direct-out, XCD swizzle, dbuf +
// 1 barrier/iter, bf16 partial O + f32 l, static-max base-2 softmax,
// s_setprio on MFMA clusters. R13: keep LDS staging. R12: no device fences.

#define SEQ 2048
#define DH 64
#define NHEADS 24
#define BN 64
#define LDK 72
#define NSLOT (NHEADS * 16 * 4)                       // 1536
#define WS_FA14  ((size_t)NSLOT * 8192 * 2 + (size_t)NSLOT * 128 * 4)

typedef float f32x4 __attribute__((ext_vector_type(4)));
typedef float f32x16 __attribute__((ext_vector_type(16)));
typedef __bf16 bf16x8 __attribute__((ext_vector_type(8)));
typedef __bf16 bf16x4 __attribute__((ext_vector_type(4)));
typedef unsigned int u32;
typedef u32 u32x4 __attribute__((ext_vector_type(4)));
typedef unsigned short u16;

#if __has_builtin(__builtin_amdgcn_exp2f)
#define EXP2F(x) __builtin_amdgcn_exp2f(x)
#else
#define EXP2F(x) exp2f(x)
#endif

#define QSCALE 0.1803368801111204f   // log2(e)/8: folds 1/sqrt(64) + base-2

static __device__ __forceinline__ u32 pk2(float a, float b) {
    u16 ua = __builtin_bit_cast(u16, (__bf16)a);
    u16 ub = __builtin_bit_cast(u16, (__bf16)b);
    return (u32)ua | ((u32)ub << 16);
}

// ---------------- main: BM=128, split-K(8), dbuf, 32x32 MFMA, reg-P ----------------
__global__ __launch_bounds__(256, 4)
void fa19_kernel(const float* __restrict__ q, const float* __restrict__ k,
                 const float* __restrict__ v,
                 __bf16* __restrict__ opart, float* __restrict__ lpart,
                 float* __restrict__ out)
{
    const int bx = blockIdx.x;             // 960 = 8 XCDs x 3 headgrp x 40
    const int xcd = bx & 7;
    const int sub = bx >> 3;               // 0..119
    const int bh = (sub / 40) * 8 + xcd;   // 3 heads pinned per XCD
    const int rem = 39 - (sub % 40);       // heavy-first within XCD
    int mt2, st;
    if      (rem >= 36) { mt2 = 15; st = 36; }
    else if (rem >= 32) { mt2 = 14; st = 32; }
    else if (rem >= 28) { mt2 = 13; st = 28; }
    else if (rem >= 24) { mt2 = 12; st = 24; }
    else if (rem >= 21) { mt2 = 11; st = 21; }
    else if (rem >= 18) { mt2 = 10; st = 18; }
    else if (rem >= 15) { mt2 = 9;  st = 15; }
    else if (rem >= 12) { mt2 = 8;  st = 12; }
    else if (rem >= 10) { mt2 = 7;  st = 10; }
    else if (rem >= 8)  { mt2 = 6;  st = 8; }
    else if (rem >= 6)  { mt2 = 5;  st = 6; }
    else if (rem >= 4)  { mt2 = 4;  st = 4; }
    else                { mt2 = rem; st = rem; }
    const int chunk = rem - st;
    const int jt0 = chunk * 8;
    const int jt_end = min(jt0 + 8, 2 * mt2 + 2);
    const int q0 = mt2 * 128;

    const int tid = threadIdx.x;
    const int w = tid >> 6, lane = tid & 63;
    const int l31 = lane & 31;
    const int hb = lane >> 5;              // 0/1 half of wave
    const bool ish = (hb != 0);

    __shared__ __bf16 Ks[2][4096];         // 16 KB double-buffered [kv][d] swz
    __shared__ __bf16 Vs[2][4096];         // 16 KB, V^T [d][kv] swz

    const float* kh = k + (size_t)bh * SEQ * DH;
    const float* vh = v + (size_t)bh * SEQ * DH;
    const int qg = q0 + w * 32 + l31;      // this lane's q-row (global)

    // Q fragments, B-operand layout for 32x32x16: col=l31, k=16ks+8hb+j
    bf16x8 qn[4];
    {
        const float* qp = q + (size_t)bh * SEQ * DH + (size_t)qg * DH + hb * 8;
        #pragma unroll
        for (int ks = 0; ks < 4; ++ks) {
            f32x4 x0 = *(const f32x4*)(qp + 16 * ks);
            f32x4 x1 = *(const f32x4*)(qp + 16 * ks + 4);
            #pragma unroll
            for (int j = 0; j < 4; ++j) {
                qn[ks][j]     = (__bf16)(x0[j] * QSCALE);
                qn[ks][4 + j] = (__bf16)(x1[j] * QSCALE);
            }
        }
    }

    f32x16 acc_o0 = {}, acc_o1 = {};       // O [q x d]: dt=0,1
    float lsum = 0.0f;                     // lane-local: q-row l31, own kv residues

    // K staging map (R11-identical): rows srow0, srow0+32
    const int srow0 = tid >> 3;
    const int sg    = tid & 7;
    const int klg   = sg ^ (srow0 & 7);

    // V staging map: thread owns 4kv x 4d; bank bits in tid[3:0]
    const int kb    = (tid & 7) * 4 + ((tid & 128) >> 2);
    const int dbase = ((tid >> 3) & 15) * 4;

    f32x4 ka[2][2], va[4];
    auto issueKV = [&](int jt) {
        const float* kp = kh + (size_t)(jt * BN + srow0) * DH + klg * 8;
        ka[0][0] = *(const f32x4*)kp;
        ka[0][1] = *(const f32x4*)(kp + 4);
        kp += 32 * DH;
        ka[1][0] = *(const f32x4*)kp;
        ka[1][1] = *(const f32x4*)(kp + 4);
        const float* vpx = vh + (size_t)(jt * BN + kb) * DH + dbase;
        #pragma unroll
        for (int ii = 0; ii < 4; ++ii) va[ii] = *(const f32x4*)(vpx + ii * DH);
    };
    auto commitKV = [&](int b) {
        #pragma unroll
        for (int s = 0; s < 2; ++s) {
            bf16x8 o;
            #pragma unroll
            for (int jj = 0; jj < 4; ++jj) {
                o[jj]     = (__bf16)ka[s][0][jj];
                o[4 + jj] = (__bf16)ka[s][1][jj];
            }
            *(bf16x8*)((char*)Ks[b] + s * 4096 + tid * 16) = o;
        }
        #pragma unroll
        for (int dd = 0; dd < 4; ++dd) {   // in-register 4x4 transpose, b64 out
            const int d = dbase + dd;
            bf16x4 p4v;
            #pragma unroll
            for (int ii = 0; ii < 4; ++ii) p4v[ii] = (__bf16)va[ii][dd];
            *(bf16x4*)((char*)Vs[b] + d * 128 +
                       ((((kb >> 3) ^ (d & 7)) << 4) | ((kb & 7) * 2))) = p4v;
        }
    };

    // ---- prologue: tile jt0 -> buf0; issue loads for jt0+1 ----
    issueKV(jt0);
    commitKV(0);
    if (jt0 + 1 < jt_end) issueKV(jt0 + 1);
    __syncthreads();

    int buf = 0;
    for (int jt = jt0; jt < jt_end; ++jt) {
        if (jt + 1 < jt_end) commitKV(buf ^ 1);
        if (jt + 2 < jt_end) issueKV(jt + 2);

        // ---- S^T = K * Q^T (2 kv-tiles x 4 k-steps, 8 MFMA) ----
        const char* Kb = (const char*)Ks[buf];
        const char* Vb = (const char*)Vs[buf];
        f32x16 sa0 = {}, sa1 = {};
        __builtin_amdgcn_s_setprio(1);
        #pragma unroll
        for (int ks = 0; ks < 4; ++ks) {
            bf16x8 kf0 = *(const bf16x8*)(Kb + l31 * 128 +
                                          (((2 * ks + hb) ^ (lane & 7)) << 4));
            bf16x8 kf1 = *(const bf16x8*)(Kb + (32 + l31) * 128 +
                                          (((2 * ks + hb) ^ (lane & 7)) << 4));
            sa0 = __builtin_amdgcn_mfma_f32_32x32x16_bf16(kf0, qn[ks], sa0, 0, 0, 0);
            sa1 = __builtin_amdgcn_mfma_f32_32x32x16_bf16(kf1, qn[ks], sa1, 0, 0, 0);
        }
        __builtin_amdgcn_s_setprio(0);

        if (jt >= 2 * mt2) {               // diagonal region: causal mask
            #pragma unroll
            for (int reg = 0; reg < 16; ++reg) {
                const int kvr = jt * 64 + (reg & 3) + 8 * (reg >> 2) + 4 * hb;
                if (kvr > qg)      sa0[reg] = -1e30f;
                if (kvr + 32 > qg) sa1[reg] = -1e30f;
            }
        }

        // ---- softmax: in-place exp2, lane-local l sum, pack to u32 quads ----
        u32 pk[8][2];                      // all static-indexed (rule #20)
        #pragma unroll
        for (int sp = 0; sp < 4; ++sp) {
            float e0 = EXP2F(sa0[4 * sp + 0]), e1 = EXP2F(sa0[4 * sp + 1]);
            float e2 = EXP2F(sa0[4 * sp + 2]), e3 = EXP2F(sa0[4 * sp + 3]);
            float f0 = EXP2F(sa1[4 * sp + 0]), f1 = EXP2F(sa1[4 * sp + 1]);
            float f2 = EXP2F(sa1[4 * sp + 2]), f3 = EXP2F(sa1[4 * sp + 3]);
            lsum += ((e0 + e1) + (e2 + e3)) + ((f0 + f1) + (f2 + f3));
            pk[sp][0]     = pk2(e0, e1); pk[sp][1]     = pk2(e2, e3);
            pk[4 + sp][0] = pk2(f0, f1); pk[4 + sp][1] = pk2(f2, f3);
        }

        // ---- O += P V. P A-frags via lane^32 exchange (bit_cast only) ----
        __builtin_amdgcn_s_setprio(1);
        #pragma unroll
        for (int s = 0; s < 4; ++s) {
            const u32 a0 = pk[2 * s][0],     a1 = pk[2 * s][1];
            const u32 b0 = pk[2 * s + 1][0], b1 = pk[2 * s + 1][1];
            const u32 sd0 = ish ? a0 : b0;
            const u32 sd1 = ish ? a1 : b1;
            const u32 r0 = (u32)__shfl_xor((int)sd0, 32, 64);
            const u32 r1 = (u32)__shfl_xor((int)sd1, 32, 64);
            u32x4 uv;
            uv[0] = ish ? r0 : a0;
            uv[1] = ish ? r1 : a1;
            uv[2] = ish ? b0 : r0;
            uv[3] = ish ? b1 : r1;
            bf16x8 pf = __builtin_bit_cast(bf16x8, uv);
            bf16x8 vf0 = *(const bf16x8*)(Vb + l31 * 128 +
                                          (((2 * s + hb) ^ (lane & 7)) << 4));
            bf16x8 vf1 = *(const bf16x8*)(Vb + (32 + l31) * 128 +
                                          (((2 * s + hb) ^ (lane & 7)) << 4));
            acc_o0 = __builtin_amdgcn_mfma_f32_32x32x16_bf16(pf, vf0, acc_o0, 0, 0, 0);
            acc_o1 = __builtin_amdgcn_mfma_f32_32x32x16_bf16(pf, vf1, acc_o1, 0, 0, 0);
        }
        __builtin_amdgcn_s_setprio(0);

        if (jt + 1 < jt_end) __syncthreads();
        buf ^= 1;
    }

    // full l for q-row l31: both kv-parity halves
    const float ltot = lsum + __shfl_xor(lsum, 32, 64);

    if (2 * mt2 + 2 <= 8) {
        // ---- single-chunk q-tile: broadcast l per C-row, write out direct
        float* oh = out + (size_t)bh * SEQ * DH;
        #pragma unroll
        for (int reg = 0; reg < 16; ++reg) {
            const int rr = (reg & 3) + 8 * (reg >> 2) + 4 * hb;
            const float lr = __shfl(ltot, rr, 64);   // lane rr holds l(q=w*32+rr)
            const float inv = 1.0f / lr;
            const int row = q0 + w * 32 + rr;
            oh[(size_t)row * DH + l31]      = acc_o0[reg] * inv;
            oh[(size_t)row * DH + 32 + l31] = acc_o1[reg] * inv;
        }
    } else {
        // ---- partials out (O in bf16; l in f32, lane-owned row) ----
        const int slot = (bh * 16 + mt2) * 4 + chunk;
        __bf16* po = opart + (size_t)slot * 8192;
        #pragma unroll
        for (int reg = 0; reg < 16; ++reg) {
            const int row = w * 32 + (reg & 3) + 8 * (reg >> 2) + 4 * hb;
            po[row * 64 + l31]      = (__bf16)acc_o0[reg];
            po[row * 64 + 32 + l31] = (__bf16)acc_o1[reg];
        }
        if (hb == 0) lpart[(size_t)slot * 128 + w * 32 + l31] = ltot;
    }
}

// ---------------- reduce: sum bf16 chunks, normalize (mt2 >= 4 only) ----------------
__global__ __launch_bounds__(256)
void fa_reduce(const __bf16* __restrict__ opart, const float* __restrict__ lpart,
               float* __restrict__ out)
{
    const int bx = blockIdx.x;             // 288 = 8 XCDs x 3 headgrp x 12
    const int xcd = bx & 7;
    const int r2 = bx >> 3;                // 0..35
    const int bh = (r2 / 12) * 8 + xcd;    // co-locate with producer XCD
    const int mt2 = 4 + (r2 % 12);
    const int nc = (mt2 >> 2) + 1;         // ceil((2*mt2+2)/8)
    const int base = (bh * 16 + mt2) * 4;
    const int tid = threadIdx.x;
    #pragma unroll
    for (int rnd = 0; rnd < 8; ++rnd) {
        const int flat = rnd * 1024 + tid * 4;
        const int row = flat >> 6;
        float o0 = 0, o1 = 0, o2 = 0, o3 = 0, l = 0;
        for (int c = 0; c < nc; ++c) {
            bf16x4 ov = *(const bf16x4*)(opart + (size_t)(base + c) * 8192 + flat);
            o0 += (float)ov[0]; o1 += (float)ov[1]; o2 += (float)ov[2]; o3 += (float)ov[3];
            l += lpart[(size_t)(base + c) * 128 + row];
        }
        const float inv = 1.0f / l;
        f32x4 res = { o0 * inv, o1 * inv, o2 * inv, o3 * inv };
        *(f32x4*)(out + (size_t)bh * SEQ * DH + (size_t)mt2 * 8192 + flat) = res;
    }
}

// ---------------- fallback: R1 self-contained kernel ----------------
__global__ __launch_bounds__(256, 2)
void fa_causal_kernel(const float* __restrict__ q, const float* __restrict__ k,
                      const float* __restrict__ v, float* __restrict__ out)
{
    const int mt = 31 - (blockIdx.x & 31);
    const int bh = blockIdx.x >> 5;
    const int tid = threadIdx.x;
    const int w = tid >> 6, lane = tid & 63;
    const int g = lane >> 4, li = lane & 15;
    const int m0 = mt * 64;
    __shared__ __bf16 KsF[BN][LDK];
    __shared__ __bf16 VsF[DH][LDK];
    __shared__ __bf16 PsF[4][16][LDK];
    const size_t head_off = (size_t)bh * SEQ * DH;
    const float* qh = q + head_off;
    const float* kh = k + head_off;
    const float* vh = v + head_off;
    float* oh = out + head_off;
    const int qrow = m0 + w * 16 + li;
    bf16x8 qf[2];
    {
        const float* qp = qh + (size_t)qrow * DH + g * 8;
        #pragma unroll
        for (int c = 0; c < 2; ++c) {
            const float* p = qp + c * 32;
            #pragma unroll
            for (int jj = 0; jj < 8; ++jj) qf[c][jj] = (__bf16)p[jj];
        }
    }
    f32x4 acc[4] = {};
    float mrow[4], lrow[4];
    #pragma unroll
    for (int r = 0; r < 4; ++r) { mrow[r] = -1e30f; lrow[r] = 0.0f; }
    const float scale = 0.125f;
    const int srow = tid >> 2, scol = (tid & 3) * 16;
    for (int jt = 0; jt <= mt; ++jt) {
        const int kv0 = jt * BN;
        __syncthreads();
        {
            const float* kp = kh + (size_t)(kv0 + srow) * DH + scol;
            __bf16 tmp[16];
            #pragma unroll
            for (int jj = 0; jj < 16; ++jj) tmp[jj] = (__bf16)kp[jj];
            *(bf16x8*)&KsF[srow][scol]     = *(bf16x8*)&tmp[0];
            *(bf16x8*)&KsF[srow][scol + 8] = *(bf16x8*)&tmp[8];
            const float* vp = vh + (size_t)(kv0 + srow) * DH + scol;
            #pragma unroll
            for (int jj = 0; jj < 16; ++jj) VsF[scol + jj][srow] = (__bf16)vp[jj];
        }
        __syncthreads();
        float s4[4][4];
        #pragma unroll
        for (int t = 0; t < 4; ++t) {
            f32x4 sa = {};
            #pragma unroll
            for (int c = 0; c < 2; ++c) {
                bf16x8 kfr = *(const bf16x8*)&KsF[t * 16 + li][c * 32 + g * 8];
                sa = __builtin_amdgcn_mfma_f32_16x16x32_bf16(qf[c], kfr, sa, 0, 0, 0);
            }
            #pragma unroll
            for (int r = 0; r < 4; ++r) s4[t][r] = sa[r] * scale;
        }
        if (jt == mt) {
            #pragma unroll
            for (int t = 0; t < 4; ++t) {
                const int col = kv0 + t * 16 + li;
                #pragma unroll
                for (int r = 0; r < 4; ++r)
                    if (col > m0 + w * 16 + g * 4 + r) s4[t][r] = -1e30f;
            }
        }
        #pragma unroll
        for (int r = 0; r < 4; ++r) {
            float mx = fmaxf(fmaxf(s4[0][r], s4[1][r]), fmaxf(s4[2][r], s4[3][r]));
            #pragma unroll
            for (int off = 1; off < 16; off <<= 1)
                mx = fmaxf(mx, __shfl_xor(mx, off, 64));
            const float mnew = fmaxf(mrow[r], mx);
            const float alpha = __expf(mrow[r] - mnew);
            mrow[r] = mnew;
            float ps = 0.0f;
            #pragma unroll
            for (int t = 0; t < 4; ++t) {
                const float p = __expf(s4[t][r] - mnew);
                s4[t][r] = p;
                ps += p;
            }
            #pragma unroll
            for (int off = 1; off < 16; off <<= 1)
                ps += __shfl_xor(ps, off, 64);
            lrow[r] = lrow[r] * alpha + ps;
            #pragma unroll
            for (int t = 0; t < 4; ++t) acc[t][r] *= alpha;
        }
        #pragma unroll
        for (int t = 0; t < 4; ++t)
            #pragma unroll
            for (int r = 0; r < 4; ++r)
                PsF[w][g * 4 + r][t * 16 + li] = (__bf16)s4[t][r];
        __syncthreads();
        #pragma unroll
        for (int c = 0; c < 2; ++c) {
            bf16x8 pf = *(const bf16x8*)&PsF[w][li][c * 32 + g * 8];
            #pragma unroll
            for (int t = 0; t < 4; ++t) {
                bf16x8 vfr = *(const bf16x8*)&VsF[t * 16 + li][c * 32 + g * 8];
                acc[t] = __builtin_amdgcn_mfma_f32_16x16x32_bf16(pf, vfr, acc[t], 0, 0, 0);
            }
        }
    }
    #pragma unroll
    for (int r = 0; r < 4; ++r) {
        const int row = m0 + w * 16 + g * 4 + r;
        const float inv = 1.0f / lrow[r];
        float* op = oh + (size_t)row * DH + li;
        #pragma unroll
        for (int t = 0; t < 4; ++t) op[t * 16] = acc[t][r] * inv;
    }
}

extern "C" void kernel_launch(void* const* d_in, const int* in_sizes, int n_in,
                              void* d_out, int out_size, void* d_ws, size_t ws_size,
                              hipStream_t stream) {
    (void)in_sizes; (void)n_in; (void)out_size;
    const float* q = (const float*)d_in[0];
    const float* k = (const float*)d_in[1];
    const float* v = (const float*)d_in[2];
    float* out = (float*)d_out;

    if (ws_size >= WS_FA14) {
        __bf16* opart = (__bf16*)d_ws;
        float* lpart = (float*)((char*)d_ws + (size_t)NSLOT * 8192 * 2);
        fa19_kernel<<<dim3(960), dim3(256), 0, stream>>>(q, k, v, opart, lpart, out);
        fa_reduce<<<dim3(288), dim3(256), 0, stream>>>(opart, lpart, out);
    } else {
        fa_causal_kernel<<<dim3(NHEADS * 32), dim3(256), 0, stream>>>(q, k, v, out);
    }
}

// Round 9
// 131.289 us; speedup vs baseline: 1.2977x; 1.2898x over previous
//
#include <hip/hip_runtime.h>
#include <hip/hip_bf16.h>

// Causal attention B=2,H=12,S=2048,D=64 fp32 in/out.
// R20 = R19 with ONE change: __launch_bounds__(256,3) on the main kernel.
// R19 post-mortem: WRITE_SIZE still 133MB + VGPR_Count=64 -> under the
// (256,4) cap (512/4=128 total, unified arch+acc file) the compiler split
// 64 arch + 64 acc and spilled the ~80 arch-side live values (sa 32 + pk 16
// + ka/va 32 + qn 16 + addr) every iteration. Peak live ~150 regs needs the
// 3-waves/SIMD cap (512/3~170). Occupancy stays 12 waves/CU = 3 blocks/CU
// (same as R17) -- but the inner loop is leaner than R17: 16 MFMA/wave/iter
// (32x32x16, ~128 cyc) vs 36 (16x16x32, ~180 cyc), zero P LDS round-trip,
// l as lane-local scalar sum (no accl MFMA).
// Carried from R19/R18: mfma_f32_32x32x16 QK+PV; S^T C-layout col=q=l&31,
// row=kv=(reg&3)+8*(reg>>2)+4h; PV A-frag kv-parity via lane^32 exchange
// (own quad 2s+h, send 2s+(1-h)); all packing via __builtin_bit_cast
// (register-only, rule #20); V^T [d][kv] 16B-XOR LDS; K layout R11; LDS
// 32KB (Ps deleted). Carried: fused prep (2 dispatches), split-K chunks of
// 8 k-tiles (960 blocks), Q-direct, single-chunk q-tiles direct-out, XCD
// swizzle (3 heads/XCD), dbuf + 1 barrier/iter, bf16 partial O + f32 l,
// static-max base-2 softmax, s_setprio on MFMA clusters.
// R13: keep LDS staging. R12: no device fences in-kernel.

#define SEQ 2048
#define DH 64
#define NHEADS 24
#define BN 64
#define LDK 72
#define NSLOT (NHEADS * 16 * 4)                       // 1536
#define WS_FA14  ((size_t)NSLOT * 8192 * 2 + (size_t)NSLOT * 128 * 4)

typedef float f32x4 __attribute__((ext_vector_type(4)));
typedef float f32x16 __attribute__((ext_vector_type(16)));
typedef __bf16 bf16x8 __attribute__((ext_vector_type(8)));
typedef __bf16 bf16x4 __attribute__((ext_vector_type(4)));
typedef unsigned int u32;
typedef u32 u32x4 __attribute__((ext_vector_type(4)));
typedef unsigned short u16;

#if __has_builtin(__builtin_amdgcn_exp2f)
#define EXP2F(x) __builtin_amdgcn_exp2f(x)
#else
#define EXP2F(x) exp2f(x)
#endif

#define QSCALE 0.1803368801111204f   // log2(e)/8: folds 1/sqrt(64) + base-2

static __device__ __forceinline__ u32 pk2(float a, float b) {
    u16 ua = __builtin_bit_cast(u16, (__bf16)a);
    u16 ub = __builtin_bit_cast(u16, (__bf16)b);
    return (u32)ua | ((u32)ub << 16);
}

// ---------------- main: BM=128, split-K(8), dbuf, 32x32 MFMA, reg-P ----------------
__global__ __launch_bounds__(256, 3)
void fa20_kernel(const float* __restrict__ q, const float* __restrict__ k,
                 const float* __restrict__ v,
                 __bf16* __restrict__ opart, float* __restrict__ lpart,
                 float* __restrict__ out)
{
    const int bx = blockIdx.x;             // 960 = 8 XCDs x 3 headgrp x 40
    const int xcd = bx & 7;
    const int sub = bx >> 3;               // 0..119
    const int bh = (sub / 40) * 8 + xcd;   // 3 heads pinned per XCD
    const int rem = 39 - (sub % 40);       // heavy-first within XCD
    int mt2, st;
    if      (rem >= 36) { mt2 = 15; st = 36; }
    else if (rem >= 32) { mt2 = 14; st = 32; }
    else if (rem >= 28) { mt2 = 13; st = 28; }
    else if (rem >= 24) { mt2 = 12; st = 24; }
    else if (rem >= 21) { mt2 = 11; st = 21; }
    else if (rem >= 18) { mt2 = 10; st = 18; }
    else if (rem >= 15) { mt2 = 9;  st = 15; }
    else if (rem >= 12) { mt2 = 8;  st = 12; }
    else if (rem >= 10) { mt2 = 7;  st = 10; }
    else if (rem >= 8)  { mt2 = 6;  st = 8; }
    else if (rem >= 6)  { mt2 = 5;  st = 6; }
    else if (rem >= 4)  { mt2 = 4;  st = 4; }
    else                { mt2 = rem; st = rem; }
    const int chunk = rem - st;
    const int jt0 = chunk * 8;
    const int jt_end = min(jt0 + 8, 2 * mt2 + 2);
    const int q0 = mt2 * 128;

    const int tid = threadIdx.x;
    const int w = tid >> 6, lane = tid & 63;
    const int l31 = lane & 31;
    const int hb = lane >> 5;              // 0/1 half of wave
    const bool ish = (hb != 0);

    __shared__ __bf16 Ks[2][4096];         // 16 KB double-buffered [kv][d] swz
    __shared__ __bf16 Vs[2][4096];         // 16 KB, V^T [d][kv] swz

    const float* kh = k + (size_t)bh * SEQ * DH;
    const float* vh = v + (size_t)bh * SEQ * DH;
    const int qg = q0 + w * 32 + l31;      // this lane's q-row (global)

    // Q fragments, B-operand layout for 32x32x16: col=l31, k=16ks+8hb+j
    bf16x8 qn[4];
    {
        const float* qp = q + (size_t)bh * SEQ * DH + (size_t)qg * DH + hb * 8;
        #pragma unroll
        for (int ks = 0; ks < 4; ++ks) {
            f32x4 x0 = *(const f32x4*)(qp + 16 * ks);
            f32x4 x1 = *(const f32x4*)(qp + 16 * ks + 4);
            #pragma unroll
            for (int j = 0; j < 4; ++j) {
                qn[ks][j]     = (__bf16)(x0[j] * QSCALE);
                qn[ks][4 + j] = (__bf16)(x1[j] * QSCALE);
            }
        }
    }

    f32x16 acc_o0 = {}, acc_o1 = {};       // O [q x d]: dt=0,1
    float lsum = 0.0f;                     // lane-local: q-row l31, own kv residues

    // K staging map (R11-identical): rows srow0, srow0+32
    const int srow0 = tid >> 3;
    const int sg    = tid & 7;
    const int klg   = sg ^ (srow0 & 7);

    // V staging map: thread owns 4kv x 4d; bank bits in tid[3:0]
    const int kb    = (tid & 7) * 4 + ((tid & 128) >> 2);
    const int dbase = ((tid >> 3) & 15) * 4;

    f32x4 ka[2][2], va[4];
    auto issueKV = [&](int jt) {
        const float* kp = kh + (size_t)(jt * BN + srow0) * DH + klg * 8;
        ka[0][0] = *(const f32x4*)kp;
        ka[0][1] = *(const f32x4*)(kp + 4);
        kp += 32 * DH;
        ka[1][0] = *(const f32x4*)kp;
        ka[1][1] = *(const f32x4*)(kp + 4);
        const float* vpx = vh + (size_t)(jt * BN + kb) * DH + dbase;
        #pragma unroll
        for (int ii = 0; ii < 4; ++ii) va[ii] = *(const f32x4*)(vpx + ii * DH);
    };
    auto commitKV = [&](int b) {
        #pragma unroll
        for (int s = 0; s < 2; ++s) {
            bf16x8 o;
            #pragma unroll
            for (int jj = 0; jj < 4; ++jj) {
                o[jj]     = (__bf16)ka[s][0][jj];
                o[4 + jj] = (__bf16)ka[s][1][jj];
            }
            *(bf16x8*)((char*)Ks[b] + s * 4096 + tid * 16) = o;
        }
        #pragma unroll
        for (int dd = 0; dd < 4; ++dd) {   // in-register 4x4 transpose, b64 out
            const int d = dbase + dd;
            bf16x4 p4v;
            #pragma unroll
            for (int ii = 0; ii < 4; ++ii) p4v[ii] = (__bf16)va[ii][dd];
            *(bf16x4*)((char*)Vs[b] + d * 128 +
                       ((((kb >> 3) ^ (d & 7)) << 4) | ((kb & 7) * 2))) = p4v;
        }
    };

    // ---- prologue: tile jt0 -> buf0; issue loads for jt0+1 ----
    issueKV(jt0);
    commitKV(0);
    if (jt0 + 1 < jt_end) issueKV(jt0 + 1);
    __syncthreads();

    int buf = 0;
    for (int jt = jt0; jt < jt_end; ++jt) {
        if (jt + 1 < jt_end) commitKV(buf ^ 1);
        if (jt + 2 < jt_end) issueKV(jt + 2);

        // ---- S^T = K * Q^T (2 kv-tiles x 4 k-steps, 8 MFMA) ----
        const char* Kb = (const char*)Ks[buf];
        const char* Vb = (const char*)Vs[buf];
        f32x16 sa0 = {}, sa1 = {};
        __builtin_amdgcn_s_setprio(1);
        #pragma unroll
        for (int ks = 0; ks < 4; ++ks) {
            bf16x8 kf0 = *(const bf16x8*)(Kb + l31 * 128 +
                                          (((2 * ks + hb) ^ (lane & 7)) << 4));
            bf16x8 kf1 = *(const bf16x8*)(Kb + (32 + l31) * 128 +
                                          (((2 * ks + hb) ^ (lane & 7)) << 4));
            sa0 = __builtin_amdgcn_mfma_f32_32x32x16_bf16(kf0, qn[ks], sa0, 0, 0, 0);
            sa1 = __builtin_amdgcn_mfma_f32_32x32x16_bf16(kf1, qn[ks], sa1, 0, 0, 0);
        }
        __builtin_amdgcn_s_setprio(0);

        if (jt >= 2 * mt2) {               // diagonal region: causal mask
            #pragma unroll
            for (int reg = 0; reg < 16; ++reg) {
                const int kvr = jt * 64 + (reg & 3) + 8 * (reg >> 2) + 4 * hb;
                if (kvr > qg)      sa0[reg] = -1e30f;
                if (kvr + 32 > qg) sa1[reg] = -1e30f;
            }
        }

        // ---- softmax: in-place exp2, lane-local l sum, pack to u32 quads ----
        u32 pk[8][2];                      // all static-indexed (rule #20)
        #pragma unroll
        for (int sp = 0; sp < 4; ++sp) {
            float e0 = EXP2F(sa0[4 * sp + 0]), e1 = EXP2F(sa0[4 * sp + 1]);
            float e2 = EXP2F(sa0[4 * sp + 2]), e3 = EXP2F(sa0[4 * sp + 3]);
            float f0 = EXP2F(sa1[4 * sp + 0]), f1 = EXP2F(sa1[4 * sp + 1]);
            float f2 = EXP2F(sa1[4 * sp + 2]), f3 = EXP2F(sa1[4 * sp + 3]);
            lsum += ((e0 + e1) + (e2 + e3)) + ((f0 + f1) + (f2 + f3));
            pk[sp][0]     = pk2(e0, e1); pk[sp][1]     = pk2(e2, e3);
            pk[4 + sp][0] = pk2(f0, f1); pk[4 + sp][1] = pk2(f2, f3);
        }

        // ---- O += P V. P A-frags via lane^32 exchange (bit_cast only) ----
        __builtin_amdgcn_s_setprio(1);
        #pragma unroll
        for (int s = 0; s < 4; ++s) {
            const u32 a0 = pk[2 * s][0],     a1 = pk[2 * s][1];
            const u32 b0 = pk[2 * s + 1][0], b1 = pk[2 * s + 1][1];
            const u32 sd0 = ish ? a0 : b0;
            const u32 sd1 = ish ? a1 : b1;
            const u32 r0 = (u32)__shfl_xor((int)sd0, 32, 64);
            const u32 r1 = (u32)__shfl_xor((int)sd1, 32, 64);
            u32x4 uv;
            uv[0] = ish ? r0 : a0;
            uv[1] = ish ? r1 : a1;
            uv[2] = ish ? b0 : r0;
            uv[3] = ish ? b1 : r1;
            bf16x8 pf = __builtin_bit_cast(bf16x8, uv);
            bf16x8 vf0 = *(const bf16x8*)(Vb + l31 * 128 +
                                          (((2 * s + hb) ^ (lane & 7)) << 4));
            bf16x8 vf1 = *(const bf16x8*)(Vb + (32 + l31) * 128 +
                                          (((2 * s + hb) ^ (lane & 7)) << 4));
            acc_o0 = __builtin_amdgcn_mfma_f32_32x32x16_bf16(pf, vf0, acc_o0, 0, 0, 0);
            acc_o1 = __builtin_amdgcn_mfma_f32_32x32x16_bf16(pf, vf1, acc_o1, 0, 0, 0);
        }
        __builtin_amdgcn_s_setprio(0);

        if (jt + 1 < jt_end) __syncthreads();
        buf ^= 1;
    }

    // full l for q-row l31: both kv-parity halves
    const float ltot = lsum + __shfl_xor(lsum, 32, 64);

    if (2 * mt2 + 2 <= 8) {
        // ---- single-chunk q-tile: broadcast l per C-row, write out direct
        float* oh = out + (size_t)bh * SEQ * DH;
        #pragma unroll
        for (int reg = 0; reg < 16; ++reg) {
            const int rr = (reg & 3) + 8 * (reg >> 2) + 4 * hb;
            const float lr = __shfl(ltot, rr, 64);   // lane rr holds l(q=w*32+rr)
            const float inv = 1.0f / lr;
            const int row = q0 + w * 32 + rr;
            oh[(size_t)row * DH + l31]      = acc_o0[reg] * inv;
            oh[(size_t)row * DH + 32 + l31] = acc_o1[reg] * inv;
        }
    } else {
        // ---- partials out (O in bf16; l in f32, lane-owned row) ----
        const int slot = (bh * 16 + mt2) * 4 + chunk;
        __bf16* po = opart + (size_t)slot * 8192;
        #pragma unroll
        for (int reg = 0; reg < 16; ++reg) {
            const int row = w * 32 + (reg & 3) + 8 * (reg >> 2) + 4 * hb;
            po[row * 64 + l31]      = (__bf16)acc_o0[reg];
            po[row * 64 + 32 + l31] = (__bf16)acc_o1[reg];
        }
        if (hb == 0) lpart[(size_t)slot * 128 + w * 32 + l31] = ltot;
    }
}

// ---------------- reduce: sum bf16 chunks, normalize (mt2 >= 4 only) ----------------
__global__ __launch_bounds__(256)
void fa_reduce(const __bf16* __restrict__ opart, const float* __restrict__ lpart,
               float* __restrict__ out)
{
    const int bx = blockIdx.x;             // 288 = 8 XCDs x 3 headgrp x 12
    const int xcd = bx & 7;
    const int r2 = bx >> 3;                // 0..35
    const int bh = (r2 / 12) * 8 + xcd;    // co-locate with producer XCD
    const int mt2 = 4 + (r2 % 12);
    const int nc = (mt2 >> 2) + 1;         // ceil((2*mt2+2)/8)
    const int base = (bh * 16 + mt2) * 4;
    const int tid = threadIdx.x;
    #pragma unroll
    for (int rnd = 0; rnd < 8; ++rnd) {
        const int flat = rnd * 1024 + tid * 4;
        const int row = flat >> 6;
        float o0 = 0, o1 = 0, o2 = 0, o3 = 0, l = 0;
        for (int c = 0; c < nc; ++c) {
            bf16x4 ov = *(const bf16x4*)(opart + (size_t)(base + c) * 8192 + flat);
            o0 += (float)ov[0]; o1 += (float)ov[1]; o2 += (float)ov[2]; o3 += (float)ov[3];
            l += lpart[(size_t)(base + c) * 128 + row];
        }
        const float inv = 1.0f / l;
        f32x4 res = { o0 * inv, o1 * inv, o2 * inv, o3 * inv };
        *(f32x4*)(out + (size_t)bh * SEQ * DH + (size_t)mt2 * 8192 + flat) = res;
    }
}

// ---------------- fallback: R1 self-contained kernel ----------------
__global__ __launch_bounds__(256, 2)
void fa_causal_kernel(const float* __restrict__ q, const float* __restrict__ k,
                      const float* __restrict__ v, float* __restrict__ out)
{
    const int mt = 31 - (blockIdx.x & 31);
    const int bh = blockIdx.x >> 5;
    const int tid = threadIdx.x;
    const int w = tid >> 6, lane = tid & 63;
    const int g = lane >> 4, li = lane & 15;
    const int m0 = mt * 64;
    __shared__ __bf16 KsF[BN][LDK];
    __shared__ __bf16 VsF[DH][LDK];
    __shared__ __bf16 PsF[4][16][LDK];
    const size_t head_off = (size_t)bh * SEQ * DH;
    const float* qh = q + head_off;
    const float* kh = k + head_off;
    const float* vh = v + head_off;
    float* oh = out + head_off;
    const int qrow = m0 + w * 16 + li;
    bf16x8 qf[2];
    {
        const float* qp = qh + (size_t)qrow * DH + g * 8;
        #pragma unroll
        for (int c = 0; c < 2; ++c) {
            const float* p = qp + c * 32;
            #pragma unroll
            for (int jj = 0; jj < 8; ++jj) qf[c][jj] = (__bf16)p[jj];
        }
    }
    f32x4 acc[4] = {};
    float mrow[4], lrow[4];
    #pragma unroll
    for (int r = 0; r < 4; ++r) { mrow[r] = -1e30f; lrow[r] = 0.0f; }
    const float scale = 0.125f;
    const int srow = tid >> 2, scol = (tid & 3) * 16;
    for (int jt = 0; jt <= mt; ++jt) {
        const int kv0 = jt * BN;
        __syncthreads();
        {
            const float* kp = kh + (size_t)(kv0 + srow) * DH + scol;
            __bf16 tmp[16];
            #pragma unroll
            for (int jj = 0; jj < 16; ++jj) tmp[jj] = (__bf16)kp[jj];
            *(bf16x8*)&KsF[srow][scol]     = *(bf16x8*)&tmp[0];
            *(bf16x8*)&KsF[srow][scol + 8] = *(bf16x8*)&tmp[8];
            const float* vp = vh + (size_t)(kv0 + srow) * DH + scol;
            #pragma unroll
            for (int jj = 0; jj < 16; ++jj) VsF[scol + jj][srow] = (__bf16)vp[jj];
        }
        __syncthreads();
        float s4[4][4];
        #pragma unroll
        for (int t = 0; t < 4; ++t) {
            f32x4 sa = {};
            #pragma unroll
            for (int c = 0; c < 2; ++c) {
                bf16x8 kfr = *(const bf16x8*)&KsF[t * 16 + li][c * 32 + g * 8];
                sa = __builtin_amdgcn_mfma_f32_16x16x32_bf16(qf[c], kfr, sa, 0, 0, 0);
            }
            #pragma unroll
            for (int r = 0; r < 4; ++r) s4[t][r] = sa[r] * scale;
        }
        if (jt == mt) {
            #pragma unroll
            for (int t = 0; t < 4; ++t) {
                const int col = kv0 + t * 16 + li;
                #pragma unroll
                for (int r = 0; r < 4; ++r)
                    if (col > m0 + w * 16 + g * 4 + r) s4[t][r] = -1e30f;
            }
        }
        #pragma unroll
        for (int r = 0; r < 4; ++r) {
            float mx = fmaxf(fmaxf(s4[0][r], s4[1][r]), fmaxf(s4[2][r], s4[3][r]));
            #pragma unroll
            for (int off = 1; off < 16; off <<= 1)
                mx = fmaxf(mx, __shfl_xor(mx, off, 64));
            const float mnew = fmaxf(mrow[r], mx);
            const float alpha = __expf(mrow[r] - mnew);
            mrow[r] = mnew;
            float ps = 0.0f;
            #pragma unroll
            for (int t = 0; t < 4; ++t) {
                const float p = __expf(s4[t][r] - mnew);
                s4[t][r] = p;
                ps += p;
            }
            #pragma unroll
            for (int off = 1; off < 16; off <<= 1)
                ps += __shfl_xor(ps, off, 64);
            lrow[r] = lrow[r] * alpha + ps;
            #pragma unroll
            for (int t = 0; t < 4; ++t) acc[t][r] *= alpha;
        }
        #pragma unroll
        for (int t = 0; t < 4; ++t)
            #pragma unroll
            for (int r = 0; r < 4; ++r)
                PsF[w][g * 4 + r][t * 16 + li] = (__bf16)s4[t][r];
        __syncthreads();
        #pragma unroll
        for (int c = 0; c < 2; ++c) {
            bf16x8 pf = *(const bf16x8*)&PsF[w][li][c * 32 + g * 8];
            #pragma unroll
            for (int t = 0; t < 4; ++t) {
                bf16x8 vfr = *(const bf16x8*)&VsF[t * 16 + li][c * 32 + g * 8];
                acc[t] = __builtin_amdgcn_mfma_f32_16x16x32_bf16(pf, vfr, acc[t], 0, 0, 0);
            }
        }
    }
    #pragma unroll
    for (int r = 0; r < 4; ++r) {
        const int row = m0 + w * 16 + g * 4 + r;
        const float inv = 1.0f / lrow[r];
        float* op = oh + (size_t)row * DH + li;
        #pragma unroll
        for (int t = 0; t < 4; ++t) op[t * 16] = acc[t][r] * inv;
    }
}

extern "C" void kernel_launch(void* const* d_in, const int* in_sizes, int n_in,
                              void* d_out, int out_size, void* d_ws, size_t ws_size,
                              hipStream_t stream) {
    (void)in_sizes; (void)n_in; (void)out_size;
    const float* q = (const float*)d_in[0];
    const float* k = (const float*)d_in[1];
    const float* v = (const float*)d_in[2];
    float* out = (float*)d_out;

    if (ws_size >= WS_FA14) {
        __bf16* opart = (__bf16*)d_ws;
        float* lpart = (float*)((char*)d_ws + (size_t)NSLOT * 8192 * 2);
        fa20_kernel<<<dim3(960), dim3(256), 0, stream>>>(q, k, v, opart, lpart, out);
        fa_reduce<<<dim3(288), dim3(256), 0, stream>>>(opart, lpart, out);
    } else {
        fa_causal_kernel<<<dim3(NHEADS * 32), dim3(256), 0, stream>>>(q, k, v, out);
    }
}

// Round 10
// 129.664 us; speedup vs baseline: 1.3140x; 1.0125x over previous
//
#include <hip/hip_runtime.h>
#include <hip/hip_bf16.h>

// Causal attention B=2,H=12,S=2048,D=64 fp32 in/out.
// R21 = R20 (spill-free 32x32 reg-P, fa 41.5us) with the lane^32 P exchange
// DELETED via kv-permuted V layout. Mechanism: MFMA sums over all k-slots,
// so the slot->kv bijection is free; choose kappa(s,hb,j) = kv each lane
// half ALREADY holds from the S^T C-layout: j<4 -> 16s+4hb+j, j>=4 ->
// 16s+8+4hb+(j-4) (bijective per 64-kv tile). PV A-frag becomes
// {pk[2s],pk[2s+1]} bit_cast directly -- zero shfl, zero selects, zero
// cross-lane dep between softmax and PV MFMAs (R20 had 8 shfl + ~24 sel
// fully serial there; VALUBusy 27.7%). B-side: V slot row r holds actual
// kv = swapbits23(r) -- implemented by loading global V row swapbits23(kb)
// for LDS slot row kb (bits1:0 pass; thread's 4 rows stay contiguous; LDS
// write/read addressing byte-identical to R20; slot(s,hb,j) -> kv =
// kappa(s,hb,j) verified algebraically).
// R20 lesson: unified VGPR file -- (256,4) cap 128 total (arch+acc) spills
// this structure; (256,3) cap ~170 fits (VGPR 84 arch + 32 acc, WRITE 17MB
// clean). R19 lesson: no address-of-local vector reinterprets (bit_cast
// only). Carried: mfma_f32_32x32x16 QK+PV, S^T C-layout col=q=l&31,
// row=kv=(reg&3)+8*(reg>>2)+4hb; l = lane-local f32 sum (+1 epilogue shfl);
// V^T [d][kv] 16B-XOR LDS; K layout R11; LDS 32KB; fused prep (2
// dispatches); split-K chunks of 8 k-tiles (960 blocks); Q-direct;
// single-chunk q-tiles direct-out; XCD swizzle (3 heads/XCD); dbuf +
// 1 barrier/iter; bf16 partial O + f32 l; static-max base-2 softmax;
// s_setprio on MFMA clusters. R13: keep LDS staging. R12: no device fences.

#define SEQ 2048
#define DH 64
#define NHEADS 24
#define BN 64
#define LDK 72
#define NSLOT (NHEADS * 16 * 4)                       // 1536
#define WS_FA14  ((size_t)NSLOT * 8192 * 2 + (size_t)NSLOT * 128 * 4)

typedef float f32x4 __attribute__((ext_vector_type(4)));
typedef float f32x16 __attribute__((ext_vector_type(16)));
typedef __bf16 bf16x8 __attribute__((ext_vector_type(8)));
typedef __bf16 bf16x4 __attribute__((ext_vector_type(4)));
typedef unsigned int u32;
typedef u32 u32x4 __attribute__((ext_vector_type(4)));
typedef unsigned short u16;

#if __has_builtin(__builtin_amdgcn_exp2f)
#define EXP2F(x) __builtin_amdgcn_exp2f(x)
#else
#define EXP2F(x) exp2f(x)
#endif

#define QSCALE 0.1803368801111204f   // log2(e)/8: folds 1/sqrt(64) + base-2

static __device__ __forceinline__ u32 pk2(float a, float b) {
    u16 ua = __builtin_bit_cast(u16, (__bf16)a);
    u16 ub = __builtin_bit_cast(u16, (__bf16)b);
    return (u32)ua | ((u32)ub << 16);
}

// ---------------- main: BM=128, split-K(8), dbuf, 32x32 MFMA, reg-P ----------------
__global__ __launch_bounds__(256, 3)
void fa21_kernel(const float* __restrict__ q, const float* __restrict__ k,
                 const float* __restrict__ v,
                 __bf16* __restrict__ opart, float* __restrict__ lpart,
                 float* __restrict__ out)
{
    const int bx = blockIdx.x;             // 960 = 8 XCDs x 3 headgrp x 40
    const int xcd = bx & 7;
    const int sub = bx >> 3;               // 0..119
    const int bh = (sub / 40) * 8 + xcd;   // 3 heads pinned per XCD
    const int rem = 39 - (sub % 40);       // heavy-first within XCD
    int mt2, st;
    if      (rem >= 36) { mt2 = 15; st = 36; }
    else if (rem >= 32) { mt2 = 14; st = 32; }
    else if (rem >= 28) { mt2 = 13; st = 28; }
    else if (rem >= 24) { mt2 = 12; st = 24; }
    else if (rem >= 21) { mt2 = 11; st = 21; }
    else if (rem >= 18) { mt2 = 10; st = 18; }
    else if (rem >= 15) { mt2 = 9;  st = 15; }
    else if (rem >= 12) { mt2 = 8;  st = 12; }
    else if (rem >= 10) { mt2 = 7;  st = 10; }
    else if (rem >= 8)  { mt2 = 6;  st = 8; }
    else if (rem >= 6)  { mt2 = 5;  st = 6; }
    else if (rem >= 4)  { mt2 = 4;  st = 4; }
    else                { mt2 = rem; st = rem; }
    const int chunk = rem - st;
    const int jt0 = chunk * 8;
    const int jt_end = min(jt0 + 8, 2 * mt2 + 2);
    const int q0 = mt2 * 128;

    const int tid = threadIdx.x;
    const int w = tid >> 6, lane = tid & 63;
    const int l31 = lane & 31;
    const int hb = lane >> 5;              // 0/1 half of wave

    __shared__ __bf16 Ks[2][4096];         // 16 KB double-buffered [kv][d] swz
    __shared__ __bf16 Vs[2][4096];         // 16 KB, V^T [d][kv-slot] swz

    const float* kh = k + (size_t)bh * SEQ * DH;
    const float* vh = v + (size_t)bh * SEQ * DH;
    const int qg = q0 + w * 32 + l31;      // this lane's q-row (global)

    // Q fragments, B-operand layout for 32x32x16: col=l31, k=16ks+8hb+j
    bf16x8 qn[4];
    {
        const float* qp = q + (size_t)bh * SEQ * DH + (size_t)qg * DH + hb * 8;
        #pragma unroll
        for (int ks = 0; ks < 4; ++ks) {
            f32x4 x0 = *(const f32x4*)(qp + 16 * ks);
            f32x4 x1 = *(const f32x4*)(qp + 16 * ks + 4);
            #pragma unroll
            for (int j = 0; j < 4; ++j) {
                qn[ks][j]     = (__bf16)(x0[j] * QSCALE);
                qn[ks][4 + j] = (__bf16)(x1[j] * QSCALE);
            }
        }
    }

    f32x16 acc_o0 = {}, acc_o1 = {};       // O [q x d]: dt=0,1
    float lsum = 0.0f;                     // lane-local: q-row l31, own kv residues

    // K staging map (R11-identical): rows srow0, srow0+32
    const int srow0 = tid >> 3;
    const int sg    = tid & 7;
    const int klg   = sg ^ (srow0 & 7);

    // V staging map: thread owns 4 slot-rows x 4d; bank bits in tid[3:0].
    // Slot row r holds GLOBAL kv = swapbits23(r): load from kb2, store at kb.
    const int kb    = (tid & 7) * 4 + ((tid & 128) >> 2);
    const int kb2   = (kb & ~0xC) | ((kb & 4) << 1) | ((kb & 8) >> 1);
    const int dbase = ((tid >> 3) & 15) * 4;

    f32x4 ka[2][2], va[4];
    auto issueKV = [&](int jt) {
        const float* kp = kh + (size_t)(jt * BN + srow0) * DH + klg * 8;
        ka[0][0] = *(const f32x4*)kp;
        ka[0][1] = *(const f32x4*)(kp + 4);
        kp += 32 * DH;
        ka[1][0] = *(const f32x4*)kp;
        ka[1][1] = *(const f32x4*)(kp + 4);
        const float* vpx = vh + (size_t)(jt * BN + kb2) * DH + dbase;
        #pragma unroll
        for (int ii = 0; ii < 4; ++ii) va[ii] = *(const f32x4*)(vpx + ii * DH);
    };
    auto commitKV = [&](int b) {
        #pragma unroll
        for (int s = 0; s < 2; ++s) {
            bf16x8 o;
            #pragma unroll
            for (int jj = 0; jj < 4; ++jj) {
                o[jj]     = (__bf16)ka[s][0][jj];
                o[4 + jj] = (__bf16)ka[s][1][jj];
            }
            *(bf16x8*)((char*)Ks[b] + s * 4096 + tid * 16) = o;
        }
        #pragma unroll
        for (int dd = 0; dd < 4; ++dd) {   // in-register 4x4 transpose, b64 out
            const int d = dbase + dd;
            bf16x4 p4v;
            #pragma unroll
            for (int ii = 0; ii < 4; ++ii) p4v[ii] = (__bf16)va[ii][dd];
            *(bf16x4*)((char*)Vs[b] + d * 128 +
                       ((((kb >> 3) ^ (d & 7)) << 4) | ((kb & 7) * 2))) = p4v;
        }
    };

    // ---- prologue: tile jt0 -> buf0; issue loads for jt0+1 ----
    issueKV(jt0);
    commitKV(0);
    if (jt0 + 1 < jt_end) issueKV(jt0 + 1);
    __syncthreads();

    int buf = 0;
    for (int jt = jt0; jt < jt_end; ++jt) {
        if (jt + 1 < jt_end) commitKV(buf ^ 1);
        if (jt + 2 < jt_end) issueKV(jt + 2);

        // ---- S^T = K * Q^T (2 kv-tiles x 4 k-steps, 8 MFMA) ----
        const char* Kb = (const char*)Ks[buf];
        const char* Vb = (const char*)Vs[buf];
        f32x16 sa0 = {}, sa1 = {};
        __builtin_amdgcn_s_setprio(1);
        #pragma unroll
        for (int ks = 0; ks < 4; ++ks) {
            bf16x8 kf0 = *(const bf16x8*)(Kb + l31 * 128 +
                                          (((2 * ks + hb) ^ (lane & 7)) << 4));
            bf16x8 kf1 = *(const bf16x8*)(Kb + (32 + l31) * 128 +
                                          (((2 * ks + hb) ^ (lane & 7)) << 4));
            sa0 = __builtin_amdgcn_mfma_f32_32x32x16_bf16(kf0, qn[ks], sa0, 0, 0, 0);
            sa1 = __builtin_amdgcn_mfma_f32_32x32x16_bf16(kf1, qn[ks], sa1, 0, 0, 0);
        }
        __builtin_amdgcn_s_setprio(0);

        if (jt >= 2 * mt2) {               // diagonal region: causal mask
            #pragma unroll
            for (int reg = 0; reg < 16; ++reg) {
                const int kvr = jt * 64 + (reg & 3) + 8 * (reg >> 2) + 4 * hb;
                if (kvr > qg)      sa0[reg] = -1e30f;
                if (kvr + 32 > qg) sa1[reg] = -1e30f;
            }
        }

        // ---- softmax: in-place exp2, lane-local l sum, pack to u32 quads ----
        u32 pk[8][2];                      // all static-indexed (rule #20)
        #pragma unroll
        for (int sp = 0; sp < 4; ++sp) {
            float e0 = EXP2F(sa0[4 * sp + 0]), e1 = EXP2F(sa0[4 * sp + 1]);
            float e2 = EXP2F(sa0[4 * sp + 2]), e3 = EXP2F(sa0[4 * sp + 3]);
            float f0 = EXP2F(sa1[4 * sp + 0]), f1 = EXP2F(sa1[4 * sp + 1]);
            float f2 = EXP2F(sa1[4 * sp + 2]), f3 = EXP2F(sa1[4 * sp + 3]);
            lsum += ((e0 + e1) + (e2 + e3)) + ((f0 + f1) + (f2 + f3));
            pk[sp][0]     = pk2(e0, e1); pk[sp][1]     = pk2(e2, e3);
            pk[4 + sp][0] = pk2(f0, f1); pk[4 + sp][1] = pk2(f2, f3);
        }

        // ---- O += P V. A-frag = own quads directly (kv-permuted V slots) ----
        __builtin_amdgcn_s_setprio(1);
        #pragma unroll
        for (int s = 0; s < 4; ++s) {
            u32x4 uv;
            uv[0] = pk[2 * s][0];
            uv[1] = pk[2 * s][1];
            uv[2] = pk[2 * s + 1][0];
            uv[3] = pk[2 * s + 1][1];
            bf16x8 pf = __builtin_bit_cast(bf16x8, uv);
            bf16x8 vf0 = *(const bf16x8*)(Vb + l31 * 128 +
                                          (((2 * s + hb) ^ (lane & 7)) << 4));
            bf16x8 vf1 = *(const bf16x8*)(Vb + (32 + l31) * 128 +
                                          (((2 * s + hb) ^ (lane & 7)) << 4));
            acc_o0 = __builtin_amdgcn_mfma_f32_32x32x16_bf16(pf, vf0, acc_o0, 0, 0, 0);
            acc_o1 = __builtin_amdgcn_mfma_f32_32x32x16_bf16(pf, vf1, acc_o1, 0, 0, 0);
        }
        __builtin_amdgcn_s_setprio(0);

        if (jt + 1 < jt_end) __syncthreads();
        buf ^= 1;
    }

    // full l for q-row l31: both kv-parity halves
    const float ltot = lsum + __shfl_xor(lsum, 32, 64);

    if (2 * mt2 + 2 <= 8) {
        // ---- single-chunk q-tile: broadcast l per C-row, write out direct
        float* oh = out + (size_t)bh * SEQ * DH;
        #pragma unroll
        for (int reg = 0; reg < 16; ++reg) {
            const int rr = (reg & 3) + 8 * (reg >> 2) + 4 * hb;
            const float lr = __shfl(ltot, rr, 64);   // lane rr holds l(q=w*32+rr)
            const float inv = 1.0f / lr;
            const int row = q0 + w * 32 + rr;
            oh[(size_t)row * DH + l31]      = acc_o0[reg] * inv;
            oh[(size_t)row * DH + 32 + l31] = acc_o1[reg] * inv;
        }
    } else {
        // ---- partials out (O in bf16; l in f32, lane-owned row) ----
        const int slot = (bh * 16 + mt2) * 4 + chunk;
        __bf16* po = opart + (size_t)slot * 8192;
        #pragma unroll
        for (int reg = 0; reg < 16; ++reg) {
            const int row = w * 32 + (reg & 3) + 8 * (reg >> 2) + 4 * hb;
            po[row * 64 + l31]      = (__bf16)acc_o0[reg];
            po[row * 64 + 32 + l31] = (__bf16)acc_o1[reg];
        }
        if (hb == 0) lpart[(size_t)slot * 128 + w * 32 + l31] = ltot;
    }
}

// ---------------- reduce: sum bf16 chunks, normalize (mt2 >= 4 only) ----------------
__global__ __launch_bounds__(256)
void fa_reduce(const __bf16* __restrict__ opart, const float* __restrict__ lpart,
               float* __restrict__ out)
{
    const int bx = blockIdx.x;             // 288 = 8 XCDs x 3 headgrp x 12
    const int xcd = bx & 7;
    const int r2 = bx >> 3;                // 0..35
    const int bh = (r2 / 12) * 8 + xcd;    // co-locate with producer XCD
    const int mt2 = 4 + (r2 % 12);
    const int nc = (mt2 >> 2) + 1;         // ceil((2*mt2+2)/8)
    const int base = (bh * 16 + mt2) * 4;
    const int tid = threadIdx.x;
    #pragma unroll
    for (int rnd = 0; rnd < 8; ++rnd) {
        const int flat = rnd * 1024 + tid * 4;
        const int row = flat >> 6;
        float o0 = 0, o1 = 0, o2 = 0, o3 = 0, l = 0;
        for (int c = 0; c < nc; ++c) {
            bf16x4 ov = *(const bf16x4*)(opart + (size_t)(base + c) * 8192 + flat);
            o0 += (float)ov[0]; o1 += (float)ov[1]; o2 += (float)ov[2]; o3 += (float)ov[3];
            l += lpart[(size_t)(base + c) * 128 + row];
        }
        const float inv = 1.0f / l;
        f32x4 res = { o0 * inv, o1 * inv, o2 * inv, o3 * inv };
        *(f32x4*)(out + (size_t)bh * SEQ * DH + (size_t)mt2 * 8192 + flat) = res;
    }
}

// ---------------- fallback: R1 self-contained kernel ----------------
__global__ __launch_bounds__(256, 2)
void fa_causal_kernel(const float* __restrict__ q, const float* __restrict__ k,
                      const float* __restrict__ v, float* __restrict__ out)
{
    const int mt = 31 - (blockIdx.x & 31);
    const int bh = blockIdx.x >> 5;
    const int tid = threadIdx.x;
    const int w = tid >> 6, lane = tid & 63;
    const int g = lane >> 4, li = lane & 15;
    const int m0 = mt * 64;
    __shared__ __bf16 KsF[BN][LDK];
    __shared__ __bf16 VsF[DH][LDK];
    __shared__ __bf16 PsF[4][16][LDK];
    const size_t head_off = (size_t)bh * SEQ * DH;
    const float* qh = q + head_off;
    const float* kh = k + head_off;
    const float* vh = v + head_off;
    float* oh = out + head_off;
    const int qrow = m0 + w * 16 + li;
    bf16x8 qf[2];
    {
        const float* qp = qh + (size_t)qrow * DH + g * 8;
        #pragma unroll
        for (int c = 0; c < 2; ++c) {
            const float* p = qp + c * 32;
            #pragma unroll
            for (int jj = 0; jj < 8; ++jj) qf[c][jj] = (__bf16)p[jj];
        }
    }
    f32x4 acc[4] = {};
    float mrow[4], lrow[4];
    #pragma unroll
    for (int r = 0; r < 4; ++r) { mrow[r] = -1e30f; lrow[r] = 0.0f; }
    const float scale = 0.125f;
    const int srow = tid >> 2, scol = (tid & 3) * 16;
    for (int jt = 0; jt <= mt; ++jt) {
        const int kv0 = jt * BN;
        __syncthreads();
        {
            const float* kp = kh + (size_t)(kv0 + srow) * DH + scol;
            __bf16 tmp[16];
            #pragma unroll
            for (int jj = 0; jj < 16; ++jj) tmp[jj] = (__bf16)kp[jj];
            *(bf16x8*)&KsF[srow][scol]     = *(bf16x8*)&tmp[0];
            *(bf16x8*)&KsF[srow][scol + 8] = *(bf16x8*)&tmp[8];
            const float* vp = vh + (size_t)(kv0 + srow) * DH + scol;
            #pragma unroll
            for (int jj = 0; jj < 16; ++jj) VsF[scol + jj][srow] = (__bf16)vp[jj];
        }
        __syncthreads();
        float s4[4][4];
        #pragma unroll
        for (int t = 0; t < 4; ++t) {
            f32x4 sa = {};
            #pragma unroll
            for (int c = 0; c < 2; ++c) {
                bf16x8 kfr = *(const bf16x8*)&KsF[t * 16 + li][c * 32 + g * 8];
                sa = __builtin_amdgcn_mfma_f32_16x16x32_bf16(qf[c], kfr, sa, 0, 0, 0);
            }
            #pragma unroll
            for (int r = 0; r < 4; ++r) s4[t][r] = sa[r] * scale;
        }
        if (jt == mt) {
            #pragma unroll
            for (int t = 0; t < 4; ++t) {
                const int col = kv0 + t * 16 + li;
                #pragma unroll
                for (int r = 0; r < 4; ++r)
                    if (col > m0 + w * 16 + g * 4 + r) s4[t][r] = -1e30f;
            }
        }
        #pragma unroll
        for (int r = 0; r < 4; ++r) {
            float mx = fmaxf(fmaxf(s4[0][r], s4[1][r]), fmaxf(s4[2][r], s4[3][r]));
            #pragma unroll
            for (int off = 1; off < 16; off <<= 1)
                mx = fmaxf(mx, __shfl_xor(mx, off, 64));
            const float mnew = fmaxf(mrow[r], mx);
            const float alpha = __expf(mrow[r] - mnew);
            mrow[r] = mnew;
            float ps = 0.0f;
            #pragma unroll
            for (int t = 0; t < 4; ++t) {
                const float p = __expf(s4[t][r] - mnew);
                s4[t][r] = p;
                ps += p;
            }
            #pragma unroll
            for (int off = 1; off < 16; off <<= 1)
                ps += __shfl_xor(ps, off, 64);
            lrow[r] = lrow[r] * alpha + ps;
            #pragma unroll
            for (int t = 0; t < 4; ++t) acc[t][r] *= alpha;
        }
        #pragma unroll
        for (int t = 0; t < 4; ++t)
            #pragma unroll
            for (int r = 0; r < 4; ++r)
                PsF[w][g * 4 + r][t * 16 + li] = (__bf16)s4[t][r];
        __syncthreads();
        #pragma unroll
        for (int c = 0; c < 2; ++c) {
            bf16x8 pf = *(const bf16x8*)&PsF[w][li][c * 32 + g * 8];
            #pragma unroll
            for (int t = 0; t < 4; ++t) {
                bf16x8 vfr = *(const bf16x8*)&VsF[t * 16 + li][c * 32 + g * 8];
                acc[t] = __builtin_amdgcn_mfma_f32_16x16x32_bf16(pf, vfr, acc[t], 0, 0, 0);
            }
        }
    }
    #pragma unroll
    for (int r = 0; r < 4; ++r) {
        const int row = m0 + w * 16 + g * 4 + r;
        const float inv = 1.0f / lrow[r];
        float* op = oh + (size_t)row * DH + li;
        #pragma unroll
        for (int t = 0; t < 4; ++t) op[t * 16] = acc[t][r] * inv;
    }
}

extern "C" void kernel_launch(void* const* d_in, const int* in_sizes, int n_in,
                              void* d_out, int out_size, void* d_ws, size_t ws_size,
                              hipStream_t stream) {
    (void)in_sizes; (void)n_in; (void)out_size;
    const float* q = (const float*)d_in[0];
    const float* k = (const float*)d_in[1];
    const float* v = (const float*)d_in[2];
    float* out = (float*)d_out;

    if (ws_size >= WS_FA14) {
        __bf16* opart = (__bf16*)d_ws;
        float* lpart = (float*)((char*)d_ws + (size_t)NSLOT * 8192 * 2);
        fa21_kernel<<<dim3(960), dim3(256), 0, stream>>>(q, k, v, opart, lpart, out);
        fa_reduce<<<dim3(288), dim3(256), 0, stream>>>(opart, lpart, out);
    } else {
        fa_causal_kernel<<<dim3(NHEADS * 32), dim3(256), 0, stream>>>(q, k, v, out);
    }
}